// Round 3
// baseline (299.738 us; speedup 1.0000x reference)
//
#include <hip/hip_runtime.h>
#include <hip/hip_bf16.h>

#define NTOK 2048
#define DIM  1024
#define DEXP 512
#define NEXP 8
#define DSH  1024          // shared expert width
#define KH   5120          // DSH + NEXP*DEXP (packed Bg/Bu row count; Bd col count)

typedef __hip_bfloat16 bf16;
typedef __attribute__((ext_vector_type(8))) short bf16x8;
typedef __attribute__((ext_vector_type(4))) float floatx4;

// async global->LDS, 16B/lane. LDS dest = wave-uniform base + lane*16 (HW adds).
__device__ __forceinline__ void gl_lds16(const bf16* g, bf16* l) {
    __builtin_amdgcn_global_load_lds(
        (const __attribute__((address_space(1))) void*)g,
        (__attribute__((address_space(3))) void*)l, 16, 0, 0);
}

// ---------------------------------------------------------------------------
// fp32 -> bf16 flat cast (x)
// ---------------------------------------------------------------------------
__global__ __launch_bounds__(256) void cast_x_kernel(const float* __restrict__ src,
                                                     bf16* __restrict__ dst, int n4) {
    int i = blockIdx.x * 256 + threadIdx.x;
    if (i >= n4) return;
    float4 v = ((const float4*)src)[i];
    struct B4 { bf16 a, b, c, d; };
    B4 o{__float2bfloat16(v.x), __float2bfloat16(v.y),
         __float2bfloat16(v.z), __float2bfloat16(v.w)};
    ((B4*)dst)[i] = o;
}

// ---------------------------------------------------------------------------
// Pack ALL weights (transpose fp32->bf16):
//   Bg [5120][1024]: rows 0..1023 = Wg_s^T ; rows 1024+e*512+h = Wg_e[e][:,h]
//   Bu [5120][1024]: same from Wu_s / Wu_e
//   Bd [1024][5120]: cols 0..1023 = Wd_s^T ; cols 1024+e*512+k = Wd_e[e][k][:]
// ---------------------------------------------------------------------------
__global__ __launch_bounds__(256) void pack_weights(
        const float* __restrict__ Wg_s, const float* __restrict__ Wu_s,
        const float* __restrict__ Wg_e, const float* __restrict__ Wu_e,
        const float* __restrict__ Wd_s, const float* __restrict__ Wd_e,
        bf16* __restrict__ Bg, bf16* __restrict__ Bu, bf16* __restrict__ Bd) {
    __shared__ float t[32][33];
    int b = blockIdx.x;
    const float* src; bf16* dst; int C; long dstStride, dstBase; int tilesX;
    if (b < 1024)       { src = Wg_s; dst = Bg; C = 1024; dstStride = 1024; dstBase = 0; tilesX = 32; }
    else if (b < 2048)  { b -= 1024; src = Wu_s; dst = Bu; C = 1024; dstStride = 1024; dstBase = 0; tilesX = 32; }
    else if (b < 6144)  { b -= 2048; int z = b >> 9; b &= 511;
                          src = Wg_e + (long)z * DIM * DEXP; dst = Bg; C = 512;
                          dstStride = 1024; dstBase = (long)(DSH + z * DEXP) * 1024; tilesX = 16; }
    else if (b < 10240) { b -= 6144; int z = b >> 9; b &= 511;
                          src = Wu_e + (long)z * DIM * DEXP; dst = Bu; C = 512;
                          dstStride = 1024; dstBase = (long)(DSH + z * DEXP) * 1024; tilesX = 16; }
    else if (b < 11264) { b -= 10240; src = Wd_s; dst = Bd; C = 1024; dstStride = KH; dstBase = 0; tilesX = 32; }
    else                { b -= 11264; int z = b >> 9; b &= 511;
                          src = Wd_e + (long)z * DEXP * DIM; dst = Bd; C = 1024;
                          dstStride = KH; dstBase = DSH + (long)z * DEXP; tilesX = 32; }
    int tileX = b & (tilesX - 1), tileY = b / tilesX;
    int c0 = tileX * 32, r0 = tileY * 32;
    int tx = threadIdx.x & 31, ty = threadIdx.x >> 5;
#pragma unroll
    for (int i = 0; i < 4; i++)
        t[ty + i * 8][tx] = src[(long)(r0 + ty + i * 8) * C + c0 + tx];
    __syncthreads();
#pragma unroll
    for (int i = 0; i < 4; i++)
        dst[dstBase + (long)(c0 + ty + i * 8) * dstStride + r0 + tx] =
            __float2bfloat16(t[tx][ty + i * 8]);
}

// ---------------------------------------------------------------------------
// Gating: one wave/token, fp32 logits->softmax->top2. Appends token to its two
// experts' slot lists: counts[e]++, tok_list[e][slot]=t, cw[e][slot]=prob.
// Lists/cw pre-zeroed so pad slots are (tok 0, weight 0) -> harmless.
// ---------------------------------------------------------------------------
__global__ __launch_bounds__(256) void gate_kernel(const float* __restrict__ x,
                                                   const float* __restrict__ Wg,
                                                   int* __restrict__ counts,
                                                   int* __restrict__ tok_list,
                                                   float* __restrict__ cw) {
    int t = blockIdx.x * 4 + (threadIdx.x >> 6);
    int lane = threadIdx.x & 63;
    float acc[NEXP] = {0.f, 0.f, 0.f, 0.f, 0.f, 0.f, 0.f, 0.f};
    const float* xr = x + (long)t * DIM;
    for (int d = lane; d < DIM; d += 64) {
        float xv = xr[d];
        float4 w0 = *(const float4*)(Wg + d * NEXP);
        float4 w1 = *(const float4*)(Wg + d * NEXP + 4);
        acc[0] += xv * w0.x; acc[1] += xv * w0.y; acc[2] += xv * w0.z; acc[3] += xv * w0.w;
        acc[4] += xv * w1.x; acc[5] += xv * w1.y; acc[6] += xv * w1.z; acc[7] += xv * w1.w;
    }
#pragma unroll
    for (int e = 0; e < NEXP; e++)
#pragma unroll
        for (int off = 32; off; off >>= 1)
            acc[e] += __shfl_xor(acc[e], off);
    if (lane == 0) {
        float m = acc[0];
#pragma unroll
        for (int e = 1; e < NEXP; e++) m = fmaxf(m, acc[e]);
        float p[NEXP], s = 0.f;
#pragma unroll
        for (int e = 0; e < NEXP; e++) { p[e] = expf(acc[e] - m); s += p[e]; }
        float inv = 1.f / s;
#pragma unroll
        for (int e = 0; e < NEXP; e++) p[e] *= inv;
        int i1 = 0;
#pragma unroll
        for (int e = 1; e < NEXP; e++) if (p[e] > p[i1]) i1 = e;
        int i2 = (i1 == 0) ? 1 : 0;
#pragma unroll
        for (int e = 0; e < NEXP; e++) if (e != i1 && p[e] > p[i2]) i2 = e;
        int s1 = atomicAdd(counts + i1, 1);
        tok_list[i1 * NTOK + s1] = t;
        cw[i1 * NTOK + s1] = p[i1];
        int s2 = atomicAdd(counts + i2, 1);
        tok_list[i2 * NTOK + s2] = t;
        cw[i2 * NTOK + s2] = p[i2];
    }
}

// ---------------------------------------------------------------------------
// Unified gate+up SwiGLU GEMM (shared + gathered routed), tile 128x64, BK=32,
// 4 waves 2x2 (wave 64x32 for BOTH G and U). XOR-swizzled LDS (chunk c4 of row
// r lives at slot col c4^((r>>1)&3)) -> bank-conflict-free fragment reads.
// Grid 1D: b<1024 routed (e=b>>7, m=(b>>3)&15, c=b&7, exit if m*128>=count[e]);
// b>=1024 shared (m=bs>>4, c=bs&15).
// ---------------------------------------------------------------------------
__global__ __launch_bounds__(256) void gu_all(const bf16* __restrict__ X,
                                              const bf16* __restrict__ Bg,
                                              const bf16* __restrict__ Bu,
                                              const int* __restrict__ counts,
                                              const int* __restrict__ tok_list,
                                              const float* __restrict__ cw,
                                              bf16* __restrict__ Hs,
                                              bf16* __restrict__ He) {
    __shared__ __align__(16) bf16 sA[128 * 32];
    __shared__ __align__(16) bf16 sBg[64 * 32];
    __shared__ __align__(16) bf16 sBu[64 * 32];

    const int b = blockIdx.x;
    const bool routed = b < 1024;
    int e = 0, m, c;
    if (routed) {
        e = b >> 7; m = (b >> 3) & 15; c = b & 7;
        if (m * 128 >= counts[e]) return;
    } else {
        int bs = b - 1024; m = bs >> 4; c = bs & 15;
    }
    const int colB0 = routed ? (DSH + e * DEXP + c * 64) : c * 64; // row base in Bg/Bu

    const int tid = threadIdx.x;
    const int wave = tid >> 6, lane = tid & 63;
    const int wr = wave >> 1, wc = wave & 1;
    const int q = lane >> 4, l15 = lane & 15;
    const int xorv = (l15 >> 1) & 3;           // fragment-read swizzle
    const int koff = (q ^ xorv) * 8;

    // staging: lane tid fills LDS slot tid (and tid+256 for A): row r, slot-col tid&3
    const int r0 = tid >> 2, c4 = tid & 3;
    const int r1 = r0 + 64;
    const int c4s = c4 ^ ((r0 >> 1) & 3);      // ((r1>>1)&3) == ((r0>>1)&3)
    long aRow0, aRow1;
    if (routed) {
        const int* tl = tok_list + e * NTOK + m * 128;
        aRow0 = (long)tl[r0] * DIM;
        aRow1 = (long)tl[r1] * DIM;
    } else {
        aRow0 = (long)(m * 128 + r0) * DIM;
        aRow1 = (long)(m * 128 + r1) * DIM;
    }
    const long bRow = (long)(colB0 + r0) * DIM;

    floatx4 accG[4][2], accU[4][2];
    const floatx4 z4 = {0.f, 0.f, 0.f, 0.f};
#pragma unroll
    for (int i = 0; i < 4; i++)
#pragma unroll
        for (int j = 0; j < 2; j++) { accG[i][j] = z4; accU[i][j] = z4; }

    for (int k0 = 0; k0 < DIM; k0 += 32) {
        gl_lds16(X + aRow0 + k0 + c4s * 8, sA + (wave * 64) * 8);
        gl_lds16(X + aRow1 + k0 + c4s * 8, sA + (256 + wave * 64) * 8);
        gl_lds16(Bg + bRow + k0 + c4s * 8, sBg + (wave * 64) * 8);
        gl_lds16(Bu + bRow + k0 + c4s * 8, sBu + (wave * 64) * 8);
        __syncthreads();

        bf16x8 af[4], bg[2], bu[2];
#pragma unroll
        for (int rt = 0; rt < 4; rt++)
            af[rt] = *(const bf16x8*)(sA + (wr * 64 + rt * 16 + l15) * 32 + koff);
#pragma unroll
        for (int ct = 0; ct < 2; ct++) {
            int cb = (wc * 32 + ct * 16 + l15) * 32 + koff;
            bg[ct] = *(const bf16x8*)(sBg + cb);
            bu[ct] = *(const bf16x8*)(sBu + cb);
        }
#pragma unroll
        for (int rt = 0; rt < 4; rt++)
#pragma unroll
            for (int ct = 0; ct < 2; ct++) {
                accG[rt][ct] = __builtin_amdgcn_mfma_f32_16x16x32_bf16(af[rt], bg[ct], accG[rt][ct], 0, 0, 0);
                accU[rt][ct] = __builtin_amdgcn_mfma_f32_16x16x32_bf16(af[rt], bu[ct], accU[rt][ct], 0, 0, 0);
            }
        __syncthreads();
    }

    // epilogue: silu(g)*u*w  (C/D layout: col=lane&15, row=q*4+reg)
    float wv[4][4];
#pragma unroll
    for (int rt = 0; rt < 4; rt++)
#pragma unroll
        for (int r = 0; r < 4; r++) {
            int srow = wr * 64 + rt * 16 + q * 4 + r;
            wv[rt][r] = routed ? cw[e * NTOK + m * 128 + srow] : 1.0f;
        }
#pragma unroll
    for (int rt = 0; rt < 4; rt++)
#pragma unroll
        for (int ct = 0; ct < 2; ct++)
#pragma unroll
            for (int r = 0; r < 4; r++) {
                int srow = wr * 64 + rt * 16 + q * 4 + r;
                int colLoc = c * 64 + wc * 32 + ct * 16 + l15;
                float g = accG[rt][ct][r];
                float u = accU[rt][ct][r];
                float h = (g / (1.f + __expf(-g))) * u * wv[rt][r];
                if (routed)
                    He[((long)e * NTOK + m * 128 + srow) * DEXP + colLoc] = __float2bfloat16(h);
                else
                    Hs[(long)(m * 128 + srow) * DSH + colLoc] = __float2bfloat16(h);
            }
}

// ---------------------------------------------------------------------------
// Unified down GEMM (shared K=1024 from Hs; routed K=512 from He, scattered by
// tok_list). Tile 128x64, wave 64x32, acc 4x2. fp32 atomicAdd into zeroed out.
// Grid 1D: b<2048 routed (e=b>>8, m=(b>>4)&15, cc=b&15); b>=2048 shared.
// ---------------------------------------------------------------------------
__global__ __launch_bounds__(256) void down_all(const bf16* __restrict__ Hs,
                                                const bf16* __restrict__ He,
                                                const bf16* __restrict__ Bd,
                                                const int* __restrict__ counts,
                                                const int* __restrict__ tok_list,
                                                float* __restrict__ out) {
    __shared__ __align__(16) bf16 sA[128 * 32];
    __shared__ __align__(16) bf16 sB[64 * 32];

    const int b = blockIdx.x;
    const bool routed = b < 2048;
    int e = 0, m, cc;
    if (routed) {
        e = b >> 8; m = (b >> 4) & 15; cc = b & 15;
        if (m * 128 >= counts[e]) return;
    } else {
        int bs = b - 2048; m = bs >> 4; cc = bs & 15;
    }
    const bf16* A = routed ? He + (long)e * NTOK * DEXP : Hs;
    const int astr = routed ? DEXP : DSH;
    const int ksteps = routed ? (DEXP / 32) : (DSH / 32);
    const int kg0 = routed ? (DSH + e * DEXP) : 0;     // K-offset within Bd rows

    const int tid = threadIdx.x;
    const int wave = tid >> 6, lane = tid & 63;
    const int wr = wave >> 1, wc = wave & 1;
    const int q = lane >> 4, l15 = lane & 15;
    const int xorv = (l15 >> 1) & 3;
    const int koff = (q ^ xorv) * 8;

    const int r0 = tid >> 2, c4 = tid & 3;
    const int r1 = r0 + 64;
    const int c4s = c4 ^ ((r0 >> 1) & 3);
    const long aRow0 = (long)(m * 128 + r0) * astr;
    const long aRow1 = (long)(m * 128 + r1) * astr;
    const long bRow = (long)(cc * 64 + r0) * KH + kg0;

    floatx4 acc[4][2];
    const floatx4 z4 = {0.f, 0.f, 0.f, 0.f};
#pragma unroll
    for (int i = 0; i < 4; i++)
#pragma unroll
        for (int j = 0; j < 2; j++) acc[i][j] = z4;

    for (int ks = 0; ks < ksteps; ks++) {
        const int k0 = ks * 32;
        gl_lds16(A + aRow0 + k0 + c4s * 8, sA + (wave * 64) * 8);
        gl_lds16(A + aRow1 + k0 + c4s * 8, sA + (256 + wave * 64) * 8);
        gl_lds16(Bd + bRow + k0 + c4s * 8, sB + (wave * 64) * 8);
        __syncthreads();

        bf16x8 af[4], bb[2];
#pragma unroll
        for (int rt = 0; rt < 4; rt++)
            af[rt] = *(const bf16x8*)(sA + (wr * 64 + rt * 16 + l15) * 32 + koff);
#pragma unroll
        for (int ct = 0; ct < 2; ct++)
            bb[ct] = *(const bf16x8*)(sB + (wc * 32 + ct * 16 + l15) * 32 + koff);
#pragma unroll
        for (int rt = 0; rt < 4; rt++)
#pragma unroll
            for (int ct = 0; ct < 2; ct++)
                acc[rt][ct] = __builtin_amdgcn_mfma_f32_16x16x32_bf16(af[rt], bb[ct], acc[rt][ct], 0, 0, 0);
        __syncthreads();
    }

    int nrow[4][4];
#pragma unroll
    for (int rt = 0; rt < 4; rt++)
#pragma unroll
        for (int r = 0; r < 4; r++) {
            int srow = wr * 64 + rt * 16 + q * 4 + r;
            nrow[rt][r] = routed ? tok_list[e * NTOK + m * 128 + srow] : (m * 128 + srow);
        }
#pragma unroll
    for (int rt = 0; rt < 4; rt++)
#pragma unroll
        for (int ct = 0; ct < 2; ct++)
#pragma unroll
            for (int r = 0; r < 4; r++) {
                int mc = cc * 64 + wc * 32 + ct * 16 + l15;
                atomicAdd(out + (long)nrow[rt][r] * DIM + mc, acc[rt][ct][r]);
            }
}

// ---------------------------------------------------------------------------
extern "C" void kernel_launch(void* const* d_in, const int* in_sizes, int n_in,
                              void* d_out, int out_size, void* d_ws, size_t ws_size,
                              hipStream_t stream) {
    const float* x    = (const float*)d_in[0];
    const float* W_g  = (const float*)d_in[1];
    const float* Wg_e = (const float*)d_in[2];
    const float* Wu_e = (const float*)d_in[3];
    const float* Wd_e = (const float*)d_in[4];
    const float* Wg_s = (const float*)d_in[5];
    const float* Wu_s = (const float*)d_in[6];
    const float* Wd_s = (const float*)d_in[7];
    float* out = (float*)d_out;

    bf16* Xb = (bf16*)d_ws;                            // [2048,1024]
    bf16* Bg = Xb + (size_t)NTOK * DIM;                // [5120,1024]
    bf16* Bu = Bg + (size_t)KH * DIM;                  // [5120,1024]
    bf16* Bd = Bu + (size_t)KH * DIM;                  // [1024,5120]
    bf16* Hs = Bd + (size_t)DIM * KH;                  // [2048,1024]
    bf16* He = Hs + (size_t)NTOK * DSH;                // [8,2048,512]
    int*  counts   = (int*)(He + (size_t)NEXP * NTOK * DEXP);
    int*  tok_list = counts + NEXP;                    // [8,2048]
    float* cw      = (float*)(tok_list + NEXP * NTOK); // [8,2048]
    const size_t metaBytes = sizeof(int) * NEXP + sizeof(int) * NEXP * NTOK
                           + sizeof(float) * NEXP * NTOK;

    hipMemsetAsync(out, 0, (size_t)NTOK * DIM * sizeof(float), stream);
    hipMemsetAsync(counts, 0, metaBytes, stream);
    cast_x_kernel<<<(NTOK * DIM / 4 + 255) / 256, 256, 0, stream>>>(x, Xb, NTOK * DIM / 4);
    pack_weights<<<15360, 256, 0, stream>>>(Wg_s, Wu_s, Wg_e, Wu_e, Wd_s, Wd_e, Bg, Bu, Bd);
    gate_kernel<<<NTOK / 4, 256, 0, stream>>>(x, W_g, counts, tok_list, cw);
    gu_all<<<1280, 256, 0, stream>>>(Xb, Bg, Bu, counts, tok_list, cw, Hs, He);
    down_all<<<2304, 256, 0, stream>>>(Hs, He, Bd, counts, tok_list, out);
}

// Round 4
// 238.228 us; speedup vs baseline: 1.2582x; 1.2582x over previous
//
#include <hip/hip_runtime.h>
#include <hip/hip_bf16.h>

#define NTOK 2048
#define DIM  1024
#define DEXP 512
#define NEXP 8
#define DSH  1024          // shared expert width
#define KH   5120          // DSH + NEXP*DEXP (packed Bg/Bu row count; Bd col count)
#define MAXROWS 5120       // compacted routed slots upper bound (4096 + 8*127 rounded)

typedef __hip_bfloat16 bf16;
typedef __attribute__((ext_vector_type(8))) short bf16x8;
typedef __attribute__((ext_vector_type(4))) float floatx4;

// async global->LDS, 16B/lane. LDS dest = wave-uniform base + lane*16 (HW adds).
__device__ __forceinline__ void gl_lds16(const bf16* g, bf16* l) {
    __builtin_amdgcn_global_load_lds(
        (const __attribute__((address_space(1))) void*)g,
        (__attribute__((address_space(3))) void*)l, 16, 0, 0);
}

__device__ __forceinline__ float b2f(short s) {
    union { float f; unsigned u; } v;
    v.u = ((unsigned)(unsigned short)s) << 16;
    return v.f;
}

// ---------------------------------------------------------------------------
// fp32 -> bf16 flat cast (x)
// ---------------------------------------------------------------------------
__global__ __launch_bounds__(256) void cast_x_kernel(const float* __restrict__ src,
                                                     bf16* __restrict__ dst, int n4) {
    int i = blockIdx.x * 256 + threadIdx.x;
    if (i >= n4) return;
    float4 v = ((const float4*)src)[i];
    struct B4 { bf16 a, b, c, d; };
    B4 o{__float2bfloat16(v.x), __float2bfloat16(v.y),
         __float2bfloat16(v.z), __float2bfloat16(v.w)};
    ((B4*)dst)[i] = o;
}

// ---------------------------------------------------------------------------
// Pack ALL weights (transpose fp32->bf16):
//   Bg [5120][1024]: rows 0..1023 = Wg_s^T ; rows 1024+e*512+h = Wg_e[e][:,h]
//   Bu [5120][1024]: same from Wu_s / Wu_e
//   Bd [1024][5120]: cols 0..1023 = Wd_s^T ; cols 1024+e*512+k = Wd_e[e][k][:]
// ---------------------------------------------------------------------------
__global__ __launch_bounds__(256) void pack_weights(
        const float* __restrict__ Wg_s, const float* __restrict__ Wu_s,
        const float* __restrict__ Wg_e, const float* __restrict__ Wu_e,
        const float* __restrict__ Wd_s, const float* __restrict__ Wd_e,
        bf16* __restrict__ Bg, bf16* __restrict__ Bu, bf16* __restrict__ Bd) {
    __shared__ float t[32][33];
    int b = blockIdx.x;
    const float* src; bf16* dst; int C; long dstStride, dstBase; int tilesX;
    if (b < 1024)       { src = Wg_s; dst = Bg; C = 1024; dstStride = 1024; dstBase = 0; tilesX = 32; }
    else if (b < 2048)  { b -= 1024; src = Wu_s; dst = Bu; C = 1024; dstStride = 1024; dstBase = 0; tilesX = 32; }
    else if (b < 6144)  { b -= 2048; int z = b >> 9; b &= 511;
                          src = Wg_e + (long)z * DIM * DEXP; dst = Bg; C = 512;
                          dstStride = 1024; dstBase = (long)(DSH + z * DEXP) * 1024; tilesX = 16; }
    else if (b < 10240) { b -= 6144; int z = b >> 9; b &= 511;
                          src = Wu_e + (long)z * DIM * DEXP; dst = Bu; C = 512;
                          dstStride = 1024; dstBase = (long)(DSH + z * DEXP) * 1024; tilesX = 16; }
    else if (b < 11264) { b -= 10240; src = Wd_s; dst = Bd; C = 1024; dstStride = KH; dstBase = 0; tilesX = 32; }
    else                { b -= 11264; int z = b >> 9; b &= 511;
                          src = Wd_e + (long)z * DEXP * DIM; dst = Bd; C = 1024;
                          dstStride = KH; dstBase = DSH + (long)z * DEXP; tilesX = 32; }
    int tileX = b & (tilesX - 1), tileY = b / tilesX;
    int c0 = tileX * 32, r0 = tileY * 32;
    int tx = threadIdx.x & 31, ty = threadIdx.x >> 5;
#pragma unroll
    for (int i = 0; i < 4; i++)
        t[ty + i * 8][tx] = src[(long)(r0 + ty + i * 8) * C + c0 + tx];
    __syncthreads();
#pragma unroll
    for (int i = 0; i < 4; i++)
        dst[dstBase + (long)(c0 + ty + i * 8) * dstStride + r0 + tx] =
            __float2bfloat16(t[tx][ty + i * 8]);
}

// ---------------------------------------------------------------------------
// Gating: one wave/token, fp32 softmax+top2 (matches reference selection).
// Appends token to its two experts' slot lists AND records the inverse map
// tok2slot[t] = (e1, s1, e2, s2) for the final combine gather.
// ---------------------------------------------------------------------------
__global__ __launch_bounds__(256) void gate_kernel(const float* __restrict__ x,
                                                   const float* __restrict__ Wg,
                                                   int* __restrict__ counts,
                                                   int* __restrict__ tok_list,
                                                   float* __restrict__ cw,
                                                   int4* __restrict__ tok2slot) {
    int t = blockIdx.x * 4 + (threadIdx.x >> 6);
    int lane = threadIdx.x & 63;
    float acc[NEXP] = {0.f, 0.f, 0.f, 0.f, 0.f, 0.f, 0.f, 0.f};
    const float* xr = x + (long)t * DIM;
    for (int d = lane; d < DIM; d += 64) {
        float xv = xr[d];
        float4 w0 = *(const float4*)(Wg + d * NEXP);
        float4 w1 = *(const float4*)(Wg + d * NEXP + 4);
        acc[0] += xv * w0.x; acc[1] += xv * w0.y; acc[2] += xv * w0.z; acc[3] += xv * w0.w;
        acc[4] += xv * w1.x; acc[5] += xv * w1.y; acc[6] += xv * w1.z; acc[7] += xv * w1.w;
    }
#pragma unroll
    for (int e = 0; e < NEXP; e++)
#pragma unroll
        for (int off = 32; off; off >>= 1)
            acc[e] += __shfl_xor(acc[e], off);
    if (lane == 0) {
        float m = acc[0];
#pragma unroll
        for (int e = 1; e < NEXP; e++) m = fmaxf(m, acc[e]);
        float p[NEXP], s = 0.f;
#pragma unroll
        for (int e = 0; e < NEXP; e++) { p[e] = expf(acc[e] - m); s += p[e]; }
        float inv = 1.f / s;
#pragma unroll
        for (int e = 0; e < NEXP; e++) p[e] *= inv;
        int i1 = 0;
#pragma unroll
        for (int e = 1; e < NEXP; e++) if (p[e] > p[i1]) i1 = e;
        int i2 = (i1 == 0) ? 1 : 0;
#pragma unroll
        for (int e = 0; e < NEXP; e++) if (e != i1 && p[e] > p[i2]) i2 = e;
        int s1 = atomicAdd(counts + i1, 1);
        tok_list[i1 * NTOK + s1] = t;
        cw[i1 * NTOK + s1] = p[i1];
        int s2 = atomicAdd(counts + i2, 1);
        tok_list[i2 * NTOK + s2] = t;
        cw[i2 * NTOK + s2] = p[i2];
        tok2slot[t] = make_int4(i1, s1, i2, s2);
    }
}

// ---------------------------------------------------------------------------
// offs[e] = 128-rounded exclusive prefix sum of counts (compacted slot space,
// 128-padding so GEMM pad rows never cross into the next expert's region).
// ---------------------------------------------------------------------------
__global__ void scan_kernel(const int* __restrict__ counts, int* __restrict__ offs) {
    if (threadIdx.x == 0) {
        int o = 0;
#pragma unroll
        for (int e = 0; e < NEXP; e++) { offs[e] = o; o += (counts[e] + 127) & ~127; }
    }
}

// ---------------------------------------------------------------------------
// Unified gate+up SwiGLU GEMM (shared + gathered routed), tile 128x64, BK=32,
// 4 waves 2x2 (wave 64x32 for BOTH G and U). XOR-swizzled LDS -> 0 conflicts.
// Routed output rows are COMPACTED: He row = offs[e] + m*128 + srow.
// ---------------------------------------------------------------------------
__global__ __launch_bounds__(256) void gu_all(const bf16* __restrict__ X,
                                              const bf16* __restrict__ Bg,
                                              const bf16* __restrict__ Bu,
                                              const int* __restrict__ counts,
                                              const int* __restrict__ offs,
                                              const int* __restrict__ tok_list,
                                              const float* __restrict__ cw,
                                              bf16* __restrict__ Hs,
                                              bf16* __restrict__ He) {
    __shared__ __align__(16) bf16 sA[128 * 32];
    __shared__ __align__(16) bf16 sBg[64 * 32];
    __shared__ __align__(16) bf16 sBu[64 * 32];

    const int b = blockIdx.x;
    const bool routed = b < 1024;
    int e = 0, m, c;
    if (routed) {
        e = b >> 7; m = (b >> 3) & 15; c = b & 7;
        if (m * 128 >= counts[e]) return;
    } else {
        int bs = b - 1024; m = bs >> 4; c = bs & 15;
    }
    const int so = routed ? offs[e] : 0;               // compacted slot base
    const int colB0 = routed ? (DSH + e * DEXP + c * 64) : c * 64;

    const int tid = threadIdx.x;
    const int wave = tid >> 6, lane = tid & 63;
    const int wr = wave >> 1, wc = wave & 1;
    const int q = lane >> 4, l15 = lane & 15;
    const int koff = (q ^ ((l15 >> 1) & 3)) * 8;       // swizzled fragment read

    const int r0 = tid >> 2, c4 = tid & 3;
    const int r1 = r0 + 64;
    const int c4s = c4 ^ ((r0 >> 1) & 3);              // ((r1>>1)&3)==((r0>>1)&3)
    long aRow0, aRow1;
    if (routed) {
        const int* tl = tok_list + e * NTOK + m * 128;
        aRow0 = (long)tl[r0] * DIM;
        aRow1 = (long)tl[r1] * DIM;
    } else {
        aRow0 = (long)(m * 128 + r0) * DIM;
        aRow1 = (long)(m * 128 + r1) * DIM;
    }
    const long bRow = (long)(colB0 + r0) * DIM;

    floatx4 accG[4][2], accU[4][2];
    const floatx4 z4 = {0.f, 0.f, 0.f, 0.f};
#pragma unroll
    for (int i = 0; i < 4; i++)
#pragma unroll
        for (int j = 0; j < 2; j++) { accG[i][j] = z4; accU[i][j] = z4; }

    for (int k0 = 0; k0 < DIM; k0 += 32) {
        gl_lds16(X + aRow0 + k0 + c4s * 8, sA + (wave * 64) * 8);
        gl_lds16(X + aRow1 + k0 + c4s * 8, sA + (256 + wave * 64) * 8);
        gl_lds16(Bg + bRow + k0 + c4s * 8, sBg + (wave * 64) * 8);
        gl_lds16(Bu + bRow + k0 + c4s * 8, sBu + (wave * 64) * 8);
        __syncthreads();

        bf16x8 af[4], bg[2], bu[2];
#pragma unroll
        for (int rt = 0; rt < 4; rt++)
            af[rt] = *(const bf16x8*)(sA + (wr * 64 + rt * 16 + l15) * 32 + koff);
#pragma unroll
        for (int ct = 0; ct < 2; ct++) {
            int cb = (wc * 32 + ct * 16 + l15) * 32 + koff;
            bg[ct] = *(const bf16x8*)(sBg + cb);
            bu[ct] = *(const bf16x8*)(sBu + cb);
        }
#pragma unroll
        for (int rt = 0; rt < 4; rt++)
#pragma unroll
            for (int ct = 0; ct < 2; ct++) {
                accG[rt][ct] = __builtin_amdgcn_mfma_f32_16x16x32_bf16(af[rt], bg[ct], accG[rt][ct], 0, 0, 0);
                accU[rt][ct] = __builtin_amdgcn_mfma_f32_16x16x32_bf16(af[rt], bu[ct], accU[rt][ct], 0, 0, 0);
            }
        __syncthreads();
    }

    // epilogue: silu(g)*u*w  (C/D layout: col=lane&15, row=q*4+reg)
    float wv[4][4];
#pragma unroll
    for (int rt = 0; rt < 4; rt++)
#pragma unroll
        for (int r = 0; r < 4; r++) {
            int srow = wr * 64 + rt * 16 + q * 4 + r;
            wv[rt][r] = routed ? cw[e * NTOK + m * 128 + srow] : 1.0f;
        }
#pragma unroll
    for (int rt = 0; rt < 4; rt++)
#pragma unroll
        for (int ct = 0; ct < 2; ct++)
#pragma unroll
            for (int r = 0; r < 4; r++) {
                int srow = wr * 64 + rt * 16 + q * 4 + r;
                int colLoc = c * 64 + wc * 32 + ct * 16 + l15;
                float g = accG[rt][ct][r];
                float u = accU[rt][ct][r];
                float h = (g / (1.f + __expf(-g))) * u * wv[rt][r];
                if (routed)
                    He[(long)(so + m * 128 + srow) * DEXP + colLoc] = __float2bfloat16(h);
                else
                    Hs[(long)(m * 128 + srow) * DSH + colLoc] = __float2bfloat16(h);
            }
}

// ---------------------------------------------------------------------------
// Unified down GEMM, NO atomics: dense bf16 partial outputs.
//   shared: Ys[token][1024] = Hs . Bd[:,0:1024]
//   routed: Ye[slotRow][1024] = He[slotRow] . Bd_e  (slotRow = offs[e]+...)
// Tile 128x64, wave 64x32, swizzled LDS.
// ---------------------------------------------------------------------------
__global__ __launch_bounds__(256) void down_all(const bf16* __restrict__ Hs,
                                                const bf16* __restrict__ He,
                                                const bf16* __restrict__ Bd,
                                                const int* __restrict__ counts,
                                                const int* __restrict__ offs,
                                                bf16* __restrict__ Ys,
                                                bf16* __restrict__ Ye) {
    __shared__ __align__(16) bf16 sA[128 * 32];
    __shared__ __align__(16) bf16 sB[64 * 32];

    const int b = blockIdx.x;
    const bool routed = b < 2048;
    int e = 0, m, cc;
    if (routed) {
        e = b >> 8; m = (b >> 4) & 15; cc = b & 15;
        if (m * 128 >= counts[e]) return;
    } else {
        int bs = b - 2048; m = bs >> 4; cc = bs & 15;
    }
    const int so = routed ? offs[e] : 0;
    const bf16* A = routed ? He + (long)so * DEXP : Hs;
    bf16* Y = routed ? Ye + (long)so * DIM : Ys;
    const int astr = routed ? DEXP : DSH;
    const int ksteps = routed ? (DEXP / 32) : (DSH / 32);
    const int kg0 = routed ? (DSH + e * DEXP) : 0;     // K-offset within Bd rows

    const int tid = threadIdx.x;
    const int wave = tid >> 6, lane = tid & 63;
    const int wr = wave >> 1, wc = wave & 1;
    const int q = lane >> 4, l15 = lane & 15;
    const int koff = (q ^ ((l15 >> 1) & 3)) * 8;

    const int r0 = tid >> 2, c4 = tid & 3;
    const int r1 = r0 + 64;
    const int c4s = c4 ^ ((r0 >> 1) & 3);
    const long aRow0 = (long)(m * 128 + r0) * astr;
    const long aRow1 = (long)(m * 128 + r1) * astr;
    const long bRow = (long)(cc * 64 + r0) * KH + kg0;

    floatx4 acc[4][2];
    const floatx4 z4 = {0.f, 0.f, 0.f, 0.f};
#pragma unroll
    for (int i = 0; i < 4; i++)
#pragma unroll
        for (int j = 0; j < 2; j++) acc[i][j] = z4;

    for (int ks = 0; ks < ksteps; ks++) {
        const int k0 = ks * 32;
        gl_lds16(A + aRow0 + k0 + c4s * 8, sA + (wave * 64) * 8);
        gl_lds16(A + aRow1 + k0 + c4s * 8, sA + (256 + wave * 64) * 8);
        gl_lds16(Bd + bRow + k0 + c4s * 8, sB + (wave * 64) * 8);
        __syncthreads();

        bf16x8 af[4], bb[2];
#pragma unroll
        for (int rt = 0; rt < 4; rt++)
            af[rt] = *(const bf16x8*)(sA + (wr * 64 + rt * 16 + l15) * 32 + koff);
#pragma unroll
        for (int ct = 0; ct < 2; ct++)
            bb[ct] = *(const bf16x8*)(sB + (wc * 32 + ct * 16 + l15) * 32 + koff);
#pragma unroll
        for (int rt = 0; rt < 4; rt++)
#pragma unroll
            for (int ct = 0; ct < 2; ct++)
                acc[rt][ct] = __builtin_amdgcn_mfma_f32_16x16x32_bf16(af[rt], bb[ct], acc[rt][ct], 0, 0, 0);
        __syncthreads();
    }

#pragma unroll
    for (int rt = 0; rt < 4; rt++)
#pragma unroll
        for (int ct = 0; ct < 2; ct++)
#pragma unroll
            for (int r = 0; r < 4; r++) {
                int srow = wr * 64 + rt * 16 + q * 4 + r;
                int mc = cc * 64 + wc * 32 + ct * 16 + l15;
                Y[(long)(m * 128 + srow) * DIM + mc] = __float2bfloat16(acc[rt][ct][r]);
            }
}

// ---------------------------------------------------------------------------
// Final gather-combine: out[t] = Ys[t] + Ye[offs[e1]+s1] + Ye[offs[e2]+s2].
// 8 floats/thread, 16B bf16 loads, fp32 stores. No atomics anywhere.
// ---------------------------------------------------------------------------
__global__ __launch_bounds__(256) void combine_kernel(const bf16* __restrict__ Ys,
                                                      const bf16* __restrict__ Ye,
                                                      const int4* __restrict__ t2s,
                                                      const int* __restrict__ offs,
                                                      float* __restrict__ out) {
    int idx = blockIdx.x * 256 + threadIdx.x;   // NTOK*DIM/8 total
    int t = idx >> 7;
    int d = (idx & 127) * 8;
    int4 ts = t2s[t];
    bf16x8 a = *(const bf16x8*)(Ys + (long)t * DIM + d);
    bf16x8 p = *(const bf16x8*)(Ye + ((long)offs[ts.x] + ts.y) * DIM + d);
    bf16x8 r = *(const bf16x8*)(Ye + ((long)offs[ts.z] + ts.w) * DIM + d);
    float* o = out + (long)t * DIM + d;
#pragma unroll
    for (int i = 0; i < 8; i++)
        o[i] = b2f(a[i]) + b2f(p[i]) + b2f(r[i]);
}

// ---------------------------------------------------------------------------
extern "C" void kernel_launch(void* const* d_in, const int* in_sizes, int n_in,
                              void* d_out, int out_size, void* d_ws, size_t ws_size,
                              hipStream_t stream) {
    const float* x    = (const float*)d_in[0];
    const float* W_g  = (const float*)d_in[1];
    const float* Wg_e = (const float*)d_in[2];
    const float* Wu_e = (const float*)d_in[3];
    const float* Wd_e = (const float*)d_in[4];
    const float* Wd_s_dummy = nullptr; (void)Wd_s_dummy;
    const float* Wg_s = (const float*)d_in[5];
    const float* Wu_s = (const float*)d_in[6];
    const float* Wd_s = (const float*)d_in[7];
    float* out = (float*)d_out;

    bf16* Xb = (bf16*)d_ws;                            // [2048,1024]          4.0 MB
    bf16* Bg = Xb + (size_t)NTOK * DIM;                // [5120,1024]         10.5 MB
    bf16* Bu = Bg + (size_t)KH * DIM;                  // [5120,1024]         10.5 MB
    bf16* Bd = Bu + (size_t)KH * DIM;                  // [1024,5120]         10.5 MB
    bf16* Hs = Bd + (size_t)DIM * KH;                  // [2048,1024]          4.0 MB
    bf16* He = Hs + (size_t)NTOK * DSH;                // [5120,512] compact   5.2 MB
    bf16* Ys = He + (size_t)MAXROWS * DEXP;            // [2048,1024]          4.0 MB
    bf16* Ye = Ys + (size_t)NTOK * DIM;                // [5120,1024] compact 10.5 MB
    int*  counts   = (int*)(Ye + (size_t)MAXROWS * DIM);
    int*  offs     = counts + NEXP;
    int*  tok_list = offs + NEXP;                      // [8,2048]
    float* cw      = (float*)(tok_list + NEXP * NTOK); // [8,2048]
    int4* tok2slot = (int4*)(cw + NEXP * NTOK);        // [2048]
    const size_t metaBytes = sizeof(int) * 2 * NEXP
                           + sizeof(int) * NEXP * NTOK + sizeof(float) * NEXP * NTOK;

    hipMemsetAsync(counts, 0, metaBytes, stream);      // zero counts/offs/lists/cw
    cast_x_kernel<<<(NTOK * DIM / 4 + 255) / 256, 256, 0, stream>>>(x, Xb, NTOK * DIM / 4);
    pack_weights<<<15360, 256, 0, stream>>>(Wg_s, Wu_s, Wg_e, Wu_e, Wd_s, Wd_e, Bg, Bu, Bd);
    gate_kernel<<<NTOK / 4, 256, 0, stream>>>(x, W_g, counts, tok_list, cw, tok2slot);
    scan_kernel<<<1, 64, 0, stream>>>(counts, offs);
    gu_all<<<1280, 256, 0, stream>>>(Xb, Bg, Bu, counts, offs, tok_list, cw, Hs, He);
    down_all<<<2304, 256, 0, stream>>>(Hs, He, Bd, counts, offs, Ys, Ye);
    combine_kernel<<<NTOK * DIM / 8 / 256, 256, 0, stream>>>(Ys, Ye, tok2slot, offs, out);
}

// Round 5
// 208.537 us; speedup vs baseline: 1.4373x; 1.1424x over previous
//
#include <hip/hip_runtime.h>
#include <hip/hip_bf16.h>

#define NTOK 2048
#define DIM  1024
#define DEXP 512
#define NEXP 8
#define DSH  1024          // shared expert width
#define KH   5120          // DSH + NEXP*DEXP (packed Bg/Bu row count; Bd col count)
#define MAXROWS 5120       // compacted routed slots upper bound

typedef __hip_bfloat16 bf16;
typedef __attribute__((ext_vector_type(8))) short bf16x8;
typedef __attribute__((ext_vector_type(4))) float floatx4;

// async global->LDS, 16B/lane. LDS dest = wave-uniform base + lane*16 (HW adds).
__device__ __forceinline__ void gl_lds16(const bf16* g, bf16* l) {
    __builtin_amdgcn_global_load_lds(
        (const __attribute__((address_space(1))) void*)g,
        (__attribute__((address_space(3))) void*)l, 16, 0, 0);
}

__device__ __forceinline__ float b2f(short s) {
    union { float f; unsigned u; } v;
    v.u = ((unsigned)(unsigned short)s) << 16;
    return v.f;
}

struct B4 { bf16 a, b, c, d; };   // 8-byte bf16 quad

// ---------------------------------------------------------------------------
// Phase-1 gating + x cast (fused): one wave/token. fp32 logits -> softmax ->
// top-2. Writes te[t]=(e1,e2), tp[t]=(p1,p2). NO atomics. Also converts the
// token's x row to bf16 (Xb) since we already have it in registers.
// ---------------------------------------------------------------------------
__global__ __launch_bounds__(256) void gate_logits(const float* __restrict__ x,
                                                   const float* __restrict__ Wg,
                                                   bf16* __restrict__ Xb,
                                                   int2* __restrict__ te,
                                                   float2* __restrict__ tp) {
    int t = blockIdx.x * 4 + (threadIdx.x >> 6);
    int lane = threadIdx.x & 63;
    const float* xr = x + (long)t * DIM;
    bf16* xo = Xb + (long)t * DIM;
    float acc[NEXP] = {0.f, 0.f, 0.f, 0.f, 0.f, 0.f, 0.f, 0.f};
#pragma unroll
    for (int i = 0; i < 4; i++) {
        int d = lane * 4 + i * 256;
        float4 xv = *(const float4*)(xr + d);
        B4 o{__float2bfloat16(xv.x), __float2bfloat16(xv.y),
             __float2bfloat16(xv.z), __float2bfloat16(xv.w)};
        *(B4*)(xo + d) = o;
#pragma unroll
        for (int j = 0; j < 4; j++) {
            float xs = (j == 0) ? xv.x : (j == 1) ? xv.y : (j == 2) ? xv.z : xv.w;
            float4 w0 = *(const float4*)(Wg + (d + j) * NEXP);
            float4 w1 = *(const float4*)(Wg + (d + j) * NEXP + 4);
            acc[0] += xs * w0.x; acc[1] += xs * w0.y; acc[2] += xs * w0.z; acc[3] += xs * w0.w;
            acc[4] += xs * w1.x; acc[5] += xs * w1.y; acc[6] += xs * w1.z; acc[7] += xs * w1.w;
        }
    }
#pragma unroll
    for (int e = 0; e < NEXP; e++)
#pragma unroll
        for (int off = 32; off; off >>= 1)
            acc[e] += __shfl_xor(acc[e], off);
    if (lane == 0) {
        float m = acc[0];
#pragma unroll
        for (int e = 1; e < NEXP; e++) m = fmaxf(m, acc[e]);
        float p[NEXP], s = 0.f;
#pragma unroll
        for (int e = 0; e < NEXP; e++) { p[e] = expf(acc[e] - m); s += p[e]; }
        float inv = 1.f / s;
#pragma unroll
        for (int e = 0; e < NEXP; e++) p[e] *= inv;
        int i1 = 0;
#pragma unroll
        for (int e = 1; e < NEXP; e++) if (p[e] > p[i1]) i1 = e;   // strict >: lowest idx on tie
        int i2 = (i1 == 0) ? 1 : 0;
#pragma unroll
        for (int e = 0; e < NEXP; e++) if (e != i1 && p[e] > p[i2]) i2 = e;
        te[t] = make_int2(i1, i2);
        tp[t] = make_float2(p[i1], p[i2]);
    }
}

// ---------------------------------------------------------------------------
// Phase-2 slot assignment: 1 block, 8 waves; wave e scans all tokens with
// ballot prefix -> deterministic slots. Writes tok_list/cw (gathered form),
// s1a/s2a (inverse map), counts, 128-rounded offs. Zero atomics.
// ---------------------------------------------------------------------------
__global__ __launch_bounds__(512) void assign_kernel(const int2* __restrict__ te,
                                                     const float2* __restrict__ tp,
                                                     int* __restrict__ counts,
                                                     int* __restrict__ offs,
                                                     int* __restrict__ tok_list,
                                                     float* __restrict__ cw,
                                                     int* __restrict__ s1a,
                                                     int* __restrict__ s2a) {
    __shared__ int cnt[NEXP];
    const int e = threadIdx.x >> 6;
    const int lane = threadIdx.x & 63;
    int base = 0;
    for (int t0 = 0; t0 < NTOK; t0 += 64) {
        int t = t0 + lane;
        int2 ee = te[t];
        bool m1 = (ee.x == e), m2 = (ee.y == e);
        bool mt = m1 || m2;
        unsigned long long mask = __ballot(mt);
        int pre = __popcll(mask & ((1ull << lane) - 1ull));
        if (mt) {
            int slot = base + pre;
            tok_list[e * NTOK + slot] = t;
            float2 pp = tp[t];
            cw[e * NTOK + slot] = m1 ? pp.x : pp.y;
            if (m1) s1a[t] = slot; else s2a[t] = slot;
        }
        base += __popcll(mask);
    }
    if (lane == 0) cnt[e] = base;
    __syncthreads();
    if (threadIdx.x == 0) {
        int o = 0;
#pragma unroll
        for (int i = 0; i < NEXP; i++) {
            counts[i] = cnt[i];
            offs[i] = o;
            o += (cnt[i] + 127) & ~127;
        }
    }
}

// ---------------------------------------------------------------------------
// Pack ALL weights (transpose fp32->bf16), single-pass 32x32 tiles:
// float4 loads (1KB/wave-instr), bf16x4 stores. LDS stride 36 (f4-aligned).
//   Bg [5120][1024]: rows 0..1023 = Wg_s^T ; rows 1024+e*512+h = Wg_e[e][:,h]
//   Bu [5120][1024]: same from Wu_s / Wu_e
//   Bd [1024][5120]: cols 0..1023 = Wd_s^T ; cols 1024+e*512+k = Wd_e[e][k][:]
// ---------------------------------------------------------------------------
__global__ __launch_bounds__(256) void pack_weights(
        const float* __restrict__ Wg_s, const float* __restrict__ Wu_s,
        const float* __restrict__ Wg_e, const float* __restrict__ Wu_e,
        const float* __restrict__ Wd_s, const float* __restrict__ Wd_e,
        bf16* __restrict__ Bg, bf16* __restrict__ Bu, bf16* __restrict__ Bd) {
    __shared__ float t[32][36];
    int b = blockIdx.x;
    const float* src; bf16* dst; int C; long dstStride, dstBase; int tilesX;
    if (b < 1024)       { src = Wg_s; dst = Bg; C = 1024; dstStride = 1024; dstBase = 0; tilesX = 32; }
    else if (b < 2048)  { b -= 1024; src = Wu_s; dst = Bu; C = 1024; dstStride = 1024; dstBase = 0; tilesX = 32; }
    else if (b < 6144)  { b -= 2048; int z = b >> 9; b &= 511;
                          src = Wg_e + (long)z * DIM * DEXP; dst = Bg; C = 512;
                          dstStride = 1024; dstBase = (long)(DSH + z * DEXP) * 1024; tilesX = 16; }
    else if (b < 10240) { b -= 6144; int z = b >> 9; b &= 511;
                          src = Wu_e + (long)z * DIM * DEXP; dst = Bu; C = 512;
                          dstStride = 1024; dstBase = (long)(DSH + z * DEXP) * 1024; tilesX = 16; }
    else if (b < 11264) { b -= 10240; src = Wd_s; dst = Bd; C = 1024; dstStride = KH; dstBase = 0; tilesX = 32; }
    else                { b -= 11264; int z = b >> 9; b &= 511;
                          src = Wd_e + (long)z * DEXP * DIM; dst = Bd; C = 1024;
                          dstStride = KH; dstBase = DSH + (long)z * DEXP; tilesX = 32; }
    int tileX = b & (tilesX - 1), tileY = b / tilesX;
    int c0 = tileX * 32, r0 = tileY * 32;

    // load: 32 rows x 8 float4-chunks
    {
        int row = threadIdx.x >> 3, ch = threadIdx.x & 7;
        float4 v = *(const float4*)(src + (long)(r0 + row) * C + c0 + ch * 4);
        *(float4*)(&t[row][ch * 4]) = v;
    }
    __syncthreads();
    // store transposed: dst row = src col; 32 dst rows x 8 bf16x4-chunks
    {
        int dc = threadIdx.x & 31, ch = threadIdx.x >> 5;
        int j = ch * 4;
        B4 o{__float2bfloat16(t[j][dc]), __float2bfloat16(t[j + 1][dc]),
             __float2bfloat16(t[j + 2][dc]), __float2bfloat16(t[j + 3][dc])};
        *(B4*)(dst + dstBase + (long)(c0 + dc) * dstStride + r0 + j) = o;
    }
}

// ---------------------------------------------------------------------------
// Unified gate+up SwiGLU GEMM (shared + gathered routed), tile 128x64, BK=32,
// 4 waves 2x2 (wave 64x32 for BOTH G and U). XOR-swizzled LDS -> 0 conflicts.
// Routed output rows are COMPACTED: He row = offs[e] + m*128 + srow.
// ---------------------------------------------------------------------------
__global__ __launch_bounds__(256) void gu_all(const bf16* __restrict__ X,
                                              const bf16* __restrict__ Bg,
                                              const bf16* __restrict__ Bu,
                                              const int* __restrict__ counts,
                                              const int* __restrict__ offs,
                                              const int* __restrict__ tok_list,
                                              const float* __restrict__ cw,
                                              bf16* __restrict__ Hs,
                                              bf16* __restrict__ He) {
    __shared__ __align__(16) bf16 sA[128 * 32];
    __shared__ __align__(16) bf16 sBg[64 * 32];
    __shared__ __align__(16) bf16 sBu[64 * 32];

    const int b = blockIdx.x;
    const bool routed = b < 1024;
    int e = 0, m, c;
    if (routed) {
        e = b >> 7; m = (b >> 3) & 15; c = b & 7;
        if (m * 128 >= counts[e]) return;
    } else {
        int bs = b - 1024; m = bs >> 4; c = bs & 15;
    }
    const int so = routed ? offs[e] : 0;               // compacted slot base
    const int colB0 = routed ? (DSH + e * DEXP + c * 64) : c * 64;

    const int tid = threadIdx.x;
    const int wave = tid >> 6, lane = tid & 63;
    const int wr = wave >> 1, wc = wave & 1;
    const int q = lane >> 4, l15 = lane & 15;
    const int koff = (q ^ ((l15 >> 1) & 3)) * 8;       // swizzled fragment read

    const int r0 = tid >> 2, c4 = tid & 3;
    const int r1 = r0 + 64;
    const int c4s = c4 ^ ((r0 >> 1) & 3);              // ((r1>>1)&3)==((r0>>1)&3)
    long aRow0, aRow1;
    if (routed) {
        const int* tl = tok_list + e * NTOK + m * 128;
        aRow0 = (long)tl[r0] * DIM;
        aRow1 = (long)tl[r1] * DIM;
    } else {
        aRow0 = (long)(m * 128 + r0) * DIM;
        aRow1 = (long)(m * 128 + r1) * DIM;
    }
    const long bRow = (long)(colB0 + r0) * DIM;

    floatx4 accG[4][2], accU[4][2];
    const floatx4 z4 = {0.f, 0.f, 0.f, 0.f};
#pragma unroll
    for (int i = 0; i < 4; i++)
#pragma unroll
        for (int j = 0; j < 2; j++) { accG[i][j] = z4; accU[i][j] = z4; }

    for (int k0 = 0; k0 < DIM; k0 += 32) {
        gl_lds16(X + aRow0 + k0 + c4s * 8, sA + (wave * 64) * 8);
        gl_lds16(X + aRow1 + k0 + c4s * 8, sA + (256 + wave * 64) * 8);
        gl_lds16(Bg + bRow + k0 + c4s * 8, sBg + (wave * 64) * 8);
        gl_lds16(Bu + bRow + k0 + c4s * 8, sBu + (wave * 64) * 8);
        __syncthreads();

        bf16x8 af[4], bg[2], bu[2];
#pragma unroll
        for (int rt = 0; rt < 4; rt++)
            af[rt] = *(const bf16x8*)(sA + (wr * 64 + rt * 16 + l15) * 32 + koff);
#pragma unroll
        for (int ct = 0; ct < 2; ct++) {
            int cb = (wc * 32 + ct * 16 + l15) * 32 + koff;
            bg[ct] = *(const bf16x8*)(sBg + cb);
            bu[ct] = *(const bf16x8*)(sBu + cb);
        }
#pragma unroll
        for (int rt = 0; rt < 4; rt++)
#pragma unroll
            for (int ct = 0; ct < 2; ct++) {
                accG[rt][ct] = __builtin_amdgcn_mfma_f32_16x16x32_bf16(af[rt], bg[ct], accG[rt][ct], 0, 0, 0);
                accU[rt][ct] = __builtin_amdgcn_mfma_f32_16x16x32_bf16(af[rt], bu[ct], accU[rt][ct], 0, 0, 0);
            }
        __syncthreads();
    }

    // epilogue: silu(g)*u*w  (C/D layout: col=lane&15, row=q*4+reg)
    float wv[4][4];
#pragma unroll
    for (int rt = 0; rt < 4; rt++)
#pragma unroll
        for (int r = 0; r < 4; r++) {
            int srow = wr * 64 + rt * 16 + q * 4 + r;
            wv[rt][r] = routed ? cw[e * NTOK + m * 128 + srow] : 1.0f;
        }
#pragma unroll
    for (int rt = 0; rt < 4; rt++)
#pragma unroll
        for (int ct = 0; ct < 2; ct++)
#pragma unroll
            for (int r = 0; r < 4; r++) {
                int srow = wr * 64 + rt * 16 + q * 4 + r;
                int colLoc = c * 64 + wc * 32 + ct * 16 + l15;
                float g = accG[rt][ct][r];
                float u = accU[rt][ct][r];
                float h = (g / (1.f + __expf(-g))) * u * wv[rt][r];
                if (routed)
                    He[(long)(so + m * 128 + srow) * DEXP + colLoc] = __float2bfloat16(h);
                else
                    Hs[(long)(m * 128 + srow) * DSH + colLoc] = __float2bfloat16(h);
            }
}

// ---------------------------------------------------------------------------
// Unified down GEMM, NO atomics: dense bf16 partial outputs.
//   shared: Ys[token][1024] = Hs . Bd[:,0:1024]
//   routed: Ye[slotRow][1024] = He[slotRow] . Bd_e  (slotRow = offs[e]+...)
// ---------------------------------------------------------------------------
__global__ __launch_bounds__(256) void down_all(const bf16* __restrict__ Hs,
                                                const bf16* __restrict__ He,
                                                const bf16* __restrict__ Bd,
                                                const int* __restrict__ counts,
                                                const int* __restrict__ offs,
                                                bf16* __restrict__ Ys,
                                                bf16* __restrict__ Ye) {
    __shared__ __align__(16) bf16 sA[128 * 32];
    __shared__ __align__(16) bf16 sB[64 * 32];

    const int b = blockIdx.x;
    const bool routed = b < 2048;
    int e = 0, m, cc;
    if (routed) {
        e = b >> 8; m = (b >> 4) & 15; cc = b & 15;
        if (m * 128 >= counts[e]) return;
    } else {
        int bs = b - 2048; m = bs >> 4; cc = bs & 15;
    }
    const int so = routed ? offs[e] : 0;
    const bf16* A = routed ? He + (long)so * DEXP : Hs;
    bf16* Y = routed ? Ye + (long)so * DIM : Ys;
    const int astr = routed ? DEXP : DSH;
    const int ksteps = routed ? (DEXP / 32) : (DSH / 32);
    const int kg0 = routed ? (DSH + e * DEXP) : 0;     // K-offset within Bd rows

    const int tid = threadIdx.x;
    const int wave = tid >> 6, lane = tid & 63;
    const int wr = wave >> 1, wc = wave & 1;
    const int q = lane >> 4, l15 = lane & 15;
    const int koff = (q ^ ((l15 >> 1) & 3)) * 8;

    const int r0 = tid >> 2, c4 = tid & 3;
    const int r1 = r0 + 64;
    const int c4s = c4 ^ ((r0 >> 1) & 3);
    const long aRow0 = (long)(m * 128 + r0) * astr;
    const long aRow1 = (long)(m * 128 + r1) * astr;
    const long bRow = (long)(cc * 64 + r0) * KH + kg0;

    floatx4 acc[4][2];
    const floatx4 z4 = {0.f, 0.f, 0.f, 0.f};
#pragma unroll
    for (int i = 0; i < 4; i++)
#pragma unroll
        for (int j = 0; j < 2; j++) acc[i][j] = z4;

    for (int ks = 0; ks < ksteps; ks++) {
        const int k0 = ks * 32;
        gl_lds16(A + aRow0 + k0 + c4s * 8, sA + (wave * 64) * 8);
        gl_lds16(A + aRow1 + k0 + c4s * 8, sA + (256 + wave * 64) * 8);
        gl_lds16(Bd + bRow + k0 + c4s * 8, sB + (wave * 64) * 8);
        __syncthreads();

        bf16x8 af[4], bb[2];
#pragma unroll
        for (int rt = 0; rt < 4; rt++)
            af[rt] = *(const bf16x8*)(sA + (wr * 64 + rt * 16 + l15) * 32 + koff);
#pragma unroll
        for (int ct = 0; ct < 2; ct++)
            bb[ct] = *(const bf16x8*)(sB + (wc * 32 + ct * 16 + l15) * 32 + koff);
#pragma unroll
        for (int rt = 0; rt < 4; rt++)
#pragma unroll
            for (int ct = 0; ct < 2; ct++)
                acc[rt][ct] = __builtin_amdgcn_mfma_f32_16x16x32_bf16(af[rt], bb[ct], acc[rt][ct], 0, 0, 0);
        __syncthreads();
    }

#pragma unroll
    for (int rt = 0; rt < 4; rt++)
#pragma unroll
        for (int ct = 0; ct < 2; ct++)
#pragma unroll
            for (int r = 0; r < 4; r++) {
                int srow = wr * 64 + rt * 16 + q * 4 + r;
                int mc = cc * 64 + wc * 32 + ct * 16 + l15;
                Y[(long)(m * 128 + srow) * DIM + mc] = __float2bfloat16(acc[rt][ct][r]);
            }
}

// ---------------------------------------------------------------------------
// Final gather-combine: out[t] = Ys[t] + Ye[offs[e1]+s1] + Ye[offs[e2]+s2].
// ---------------------------------------------------------------------------
__global__ __launch_bounds__(256) void combine_kernel(const bf16* __restrict__ Ys,
                                                      const bf16* __restrict__ Ye,
                                                      const int2* __restrict__ te,
                                                      const int* __restrict__ s1a,
                                                      const int* __restrict__ s2a,
                                                      const int* __restrict__ offs,
                                                      float* __restrict__ out) {
    int idx = blockIdx.x * 256 + threadIdx.x;   // NTOK*DIM/8 total
    int t = idx >> 7;
    int d = (idx & 127) * 8;
    int2 ee = te[t];
    long r1 = (long)(offs[ee.x] + s1a[t]);
    long r2 = (long)(offs[ee.y] + s2a[t]);
    bf16x8 a = *(const bf16x8*)(Ys + (long)t * DIM + d);
    bf16x8 p = *(const bf16x8*)(Ye + r1 * DIM + d);
    bf16x8 r = *(const bf16x8*)(Ye + r2 * DIM + d);
    float* o = out + (long)t * DIM + d;
#pragma unroll
    for (int i = 0; i < 8; i++)
        o[i] = b2f(a[i]) + b2f(p[i]) + b2f(r[i]);
}

// ---------------------------------------------------------------------------
extern "C" void kernel_launch(void* const* d_in, const int* in_sizes, int n_in,
                              void* d_out, int out_size, void* d_ws, size_t ws_size,
                              hipStream_t stream) {
    const float* x    = (const float*)d_in[0];
    const float* W_g  = (const float*)d_in[1];
    const float* Wg_e = (const float*)d_in[2];
    const float* Wu_e = (const float*)d_in[3];
    const float* Wd_e = (const float*)d_in[4];
    const float* Wg_s = (const float*)d_in[5];
    const float* Wu_s = (const float*)d_in[6];
    const float* Wd_s = (const float*)d_in[7];
    float* out = (float*)d_out;

    bf16* Xb = (bf16*)d_ws;                            // [2048,1024]
    bf16* Bg = Xb + (size_t)NTOK * DIM;                // [5120,1024]
    bf16* Bu = Bg + (size_t)KH * DIM;                  // [5120,1024]
    bf16* Bd = Bu + (size_t)KH * DIM;                  // [1024,5120]
    bf16* Hs = Bd + (size_t)DIM * KH;                  // [2048,1024]
    bf16* He = Hs + (size_t)NTOK * DSH;                // [5120,512] compacted
    bf16* Ys = He + (size_t)MAXROWS * DEXP;            // [2048,1024]
    bf16* Ye = Ys + (size_t)NTOK * DIM;                // [5120,1024] compacted
    int*  counts   = (int*)(Ye + (size_t)MAXROWS * DIM);
    int*  offs     = counts + NEXP;
    int*  tok_list = offs + NEXP;                      // [8,2048]
    float* cw      = (float*)(tok_list + NEXP * NTOK); // [8,2048]
    int*  s1a      = (int*)(cw + NEXP * NTOK);         // [2048]
    int*  s2a      = s1a + NTOK;                       // [2048]
    int2* te       = (int2*)(s2a + NTOK);              // [2048]
    float2* tp     = (float2*)(te + NTOK);             // [2048]

    // pad slots must be (token 0, weight 0): zero tok_list + cw only
    hipMemsetAsync(tok_list, 0,
                   sizeof(int) * NEXP * NTOK + sizeof(float) * NEXP * NTOK, stream);
    gate_logits<<<NTOK / 4, 256, 0, stream>>>(x, W_g, Xb, te, tp);
    assign_kernel<<<1, 512, 0, stream>>>(te, tp, counts, offs, tok_list, cw, s1a, s2a);
    pack_weights<<<15360, 256, 0, stream>>>(Wg_s, Wu_s, Wg_e, Wu_e, Wd_s, Wd_e, Bg, Bu, Bd);
    gu_all<<<1280, 256, 0, stream>>>(Xb, Bg, Bu, counts, offs, tok_list, cw, Hs, He);
    down_all<<<2304, 256, 0, stream>>>(Hs, He, Bd, counts, offs, Ys, Ye);
    combine_kernel<<<NTOK * DIM / 8 / 256, 256, 0, stream>>>(Ys, Ye, te, s1a, s2a, offs, out);
}